// Round 2
// baseline (41019.653 us; speedup 1.0000x reference)
//
#include <hip/hip_runtime.h>
#include <cstdint>

#define Bb 256
#define Tt 512
#define Dd 128
#define Hh 512
#define BH (Bb*Hh)            // 131072
#define KGATE 640
#define NCT (Hh/16)           // 32 col-tiles per matrix
#define MATSZ (KGATE*Hh)      // 327680 elements per gate matrix slot
#define LDSB (81920 + 32768 + 3*16*33*4)   // weights + W_a slice + u_lds = 121024 B

typedef unsigned short ushort_t;
typedef __bf16 bf16x8 __attribute__((ext_vector_type(8)));
typedef unsigned short u16x8 __attribute__((ext_vector_type(8)));
typedef float f32x4 __attribute__((ext_vector_type(4)));

static __device__ inline ushort_t f2bf(float f){
    union { float f; uint32_t u; } v; v.f = f;
    uint32_t u = v.u;
    uint32_t r = (u + 0x7FFFu + ((u >> 16) & 1u)) >> 16;
    return (ushort_t)r;
}
static __device__ inline float sigmoidf_(float x){ return 1.f/(1.f+__expf(-x)); }
static __device__ inline float tanhf_(float x){
    float ax = fabsf(x);
    float t = __expf(-2.f*ax);
    float r = (1.f - t)/(1.f + t);
    return copysignf(r, x);
}
static __device__ inline bf16x8 load_x_frag(const float* xp){
    f32x4 v0 = *reinterpret_cast<const f32x4*>(xp);
    f32x4 v1 = *reinterpret_cast<const f32x4*>(xp + 4);
    u16x8 tmp;
    #pragma unroll
    for (int j = 0; j < 4; ++j){ tmp[j] = f2bf(v0[j]); tmp[4+j] = f2bf(v1[j]); }
    return __builtin_bit_cast(bf16x8, tmp);
}

// Pack one weight matrix (optionally stacked [W(128 rows); U(512 rows)]) into
// MFMA B-fragment order: elem(lane,j) = M[kb*32 + (lane>>4)*8 + j][ct*16 + (lane&15)]
__global__ void pack_mat(const float* __restrict__ Wm, const float* __restrict__ Um,
                         int Ktot, ushort_t* __restrict__ dst){
    int total = Ktot * 64;  // groups of 8 bf16
    for (int g = blockIdx.x*blockDim.x + threadIdx.x; g < total; g += gridDim.x*blockDim.x){
        int kb   = g >> 11;
        int rem  = g & 2047;
        int ct   = rem >> 6;
        int lane = rem & 63;
        int k0   = kb*32 + ((lane >> 4) << 3);
        int col  = (ct << 4) + (lane & 15);
        u16x8 o8;
        #pragma unroll
        for (int j = 0; j < 8; ++j){
            int k = k0 + j;
            float v;
            if (Um) v = (k < Dd) ? Wm[k*Hh + col] : Um[(k - Dd)*Hh + col];
            else    v = Wm[k*Hh + col];
            o8[j] = f2bf(v);
        }
        *reinterpret_cast<u16x8*>(dst + (size_t)g*8) = o8;
    }
}

__global__ void init_state2(ushort_t* hbf, uint32_t* bar){
    int i = blockIdx.x*blockDim.x + threadIdx.x;
    if (i < BH) hbf[i] = 0;
    if (i < 8) bar[i] = 0;
}

struct PK {
    const ushort_t* wpack;
    const float* X0; const float* X1; const float* X2;
    const float* bC0; const float* bC1; const float* bC2;
    const float* bI0; const float* bI1; const float* bI2;
    const float* bF; const float* bO; const float* b_a;
    ushort_t* hbf; ushort_t* l_bf; float* l_f; float* fo_f;
    uint32_t* bar; float* out;
};

static __device__ inline void group_barrier(uint32_t* ctr, uint32_t target){
    __syncthreads();
    if (threadIdx.x == 0){
        __hip_atomic_fetch_add(ctr, 1u, __ATOMIC_RELEASE, __HIP_MEMORY_SCOPE_AGENT);
        uint32_t v = __hip_atomic_load(ctr, __ATOMIC_ACQUIRE, __HIP_MEMORY_SCOPE_AGENT);
        while (v < target){
            __builtin_amdgcn_s_sleep(1);
            v = __hip_atomic_load(ctr, __ATOMIC_ACQUIRE, __HIP_MEMORY_SCOPE_AGENT);
        }
    }
    __syncthreads();
    __threadfence();
}

// 256 blocks x 256 threads, cooperative. Group g = bid>>6 owns batch rows [g*64, g*64+64).
// Within a group (gb = bid&63):
//   gb 0..47 : paired gate blocks  (stream s=gb>>4, col-slice cs=gb&15, 32 cols): c-mat + i-mat
//   gb 48..55: f-gate block (col-slice 64 wide)
//   gb 56..63: o-gate block (col-slice 64 wide)
// Phase B (all blocks): rows rs*16 (rs=gb>>4), cols c2*32 (c2=gb&15), c state in registers.
__global__ __launch_bounds__(256, 1) void lstm_persistent(PK A){
    extern __shared__ char lds[];
    ushort_t* Wlds  = (ushort_t*)lds;                    // 81920 B
    ushort_t* WaLds = (ushort_t*)(lds + 81920);          // 32768 B
    float*    u_lds = (float*)(lds + 81920 + 32768);     // 3*16*33 f32

    const int bid = blockIdx.x;
    const int g   = bid >> 6;
    const int gb  = bid & 63;
    const int tid = threadIdx.x;
    const int lane = tid & 63;
    const int wave = tid >> 6;
    const int r15  = lane & 15;
    const int khi  = (lane >> 4) << 3;
    const int grow0 = g << 6;

    const bool paired = (gb < 48);
    const int s   = gb >> 4;          // stream (valid when paired)
    const int cs  = gb & 15;          // 32-wide col slice (paired)
    const int fu  = (gb >= 56) ? 1 : 0;
    const int cfo = (gb - 48) & 7;    // 64-wide col slice (f/o)

    // ---- stage weights into LDS (once) ----
    if (paired){
        const ushort_t* base0 = A.wpack + (size_t)(4 + s)*MATSZ;  // c-mat
        const ushort_t* base1 = A.wpack + (size_t)s*MATSZ;        // i-mat
        for (int u = tid; u < 80*64; u += 256){
            int ch = u >> 6, un = u & 63;
            int m2 = (ch >= 40) ? 1 : 0;
            int rem = ch - m2*40;
            int kb = rem >> 1, j = rem & 1;
            const ushort_t* src = (m2 == 0 ? base0 : base1)
                                + ((size_t)(kb*NCT + cs*2 + j)*64 + un)*8;
            *reinterpret_cast<u16x8*>(Wlds + ((size_t)ch*64 + un)*8)
                = *reinterpret_cast<const u16x8*>(src);
        }
    } else {
        const ushort_t* base = A.wpack + (size_t)(fu == 0 ? 3 : 7)*MATSZ;
        for (int u = tid; u < 80*64; u += 256){
            int ch = u >> 6, un = u & 63;
            int kb = ch >> 2, j = ch & 3;
            const ushort_t* src = base + ((size_t)(kb*NCT + cfo*4 + j)*64 + un)*8;
            *reinterpret_cast<u16x8*>(Wlds + ((size_t)ch*64 + un)*8)
                = *reinterpret_cast<const u16x8*>(src);
        }
    }
    const int rs = gb >> 4, c2 = gb & 15;   // phase-B tile
    {
        const ushort_t* base = A.wpack + (size_t)8*MATSZ;
        for (int u = tid; u < 32*64; u += 256){
            int ch = u >> 6, un = u & 63;
            int kb = ch >> 1, j = ch & 1;
            const ushort_t* src = base + ((size_t)(kb*NCT + c2*2 + j)*64 + un)*8;
            *reinterpret_cast<u16x8*>(WaLds + ((size_t)ch*64 + un)*8)
                = *reinterpret_cast<const u16x8*>(src);
        }
    }
    __syncthreads();

    // ---- per-thread persistent state ----
    // phase A biases
    float biasA0[4] = {0,0,0,0}, biasA1[2] = {0,0};
    if (paired){
        const float* bCs = (s == 0) ? A.bC0 : (s == 1) ? A.bC1 : A.bC2;
        const float* bIs = (s == 0) ? A.bI0 : (s == 1) ? A.bI1 : A.bI2;
        #pragma unroll
        for (int fj = 0; fj < 2; ++fj){
            int col = cs*32 + fj*16 + r15;
            biasA0[fj] = bCs[col];
            biasA1[fj] = bIs[col];
        }
    } else {
        const float* bb = fu ? A.bO : A.bF;
        #pragma unroll
        for (int fj = 0; fj < 4; ++fj)
            biasA0[fj] = bb[cfo*64 + fj*16 + r15];
    }
    // phase B elementwise: element e0 = (rowE, colE), e1 = (rowE+8, colE)
    const int rowE = tid >> 5;          // 0..7
    const int colE = tid & 31;
    const int gcol = c2*32 + colE;
    const int growE0 = grow0 + rs*16 + rowE;
    const int growE1 = growE0 + 8;
    const float ba = A.b_a[gcol];
    float creg0 = 0.f, creg1 = 0.f;

    const float* Xs = paired ? ((s == 0) ? A.X0 : (s == 1) ? A.X1 : A.X2) : A.X0;
    uint32_t* ctr = A.bar + g;
    const int arow = grow0 + wave*16 + r15;      // phase-A A-frag row (global batch row)

    for (int t = 0; t < Tt; ++t){
        // ================= phase A: gate GEMMs =================
        if (paired){
            f32x4 a0[2] = {{0.f,0.f,0.f,0.f},{0.f,0.f,0.f,0.f}};
            f32x4 a1[2] = {{0.f,0.f,0.f,0.f},{0.f,0.f,0.f,0.f}};
            const float* xp = Xs + ((size_t)arow*Tt + t)*Dd + khi;
            #pragma unroll
            for (int kb = 0; kb < KGATE/32; ++kb){
                bf16x8 a;
                if (kb < 4) a = load_x_frag(xp + kb*32);
                else        a = *reinterpret_cast<const bf16x8*>(
                                  A.hbf + (size_t)arow*Hh + (kb*32 + khi - Dd));
                #pragma unroll
                for (int fj = 0; fj < 2; ++fj){
                    bf16x8 b0 = *reinterpret_cast<const bf16x8*>(Wlds + ((size_t)(kb*2 + fj))*512 + lane*8);
                    a0[fj] = __builtin_amdgcn_mfma_f32_16x16x32_bf16(a, b0, a0[fj], 0, 0, 0);
                    bf16x8 b1 = *reinterpret_cast<const bf16x8*>(Wlds + ((size_t)((20 + kb)*2 + fj))*512 + lane*8);
                    a1[fj] = __builtin_amdgcn_mfma_f32_16x16x32_bf16(a, b1, a1[fj], 0, 0, 0);
                }
            }
            #pragma unroll
            for (int fj = 0; fj < 2; ++fj)
            #pragma unroll
            for (int r = 0; r < 4; ++r){
                int lrow = wave*16 + ((lane >> 4) << 2) + r;
                int col  = cs*32 + fj*16 + r15;
                size_t idx = (size_t)(grow0 + lrow)*Hh + col;
                float l = tanhf_(a0[fj][r] + biasA0[fj]) * sigmoidf_(a1[fj][r] + biasA1[fj]);
                A.l_f [(size_t)s*BH + idx] = l;
                A.l_bf[(size_t)s*BH + idx] = f2bf(l);
            }
        } else {
            f32x4 ac[4] = {{0.f,0.f,0.f,0.f},{0.f,0.f,0.f,0.f},{0.f,0.f,0.f,0.f},{0.f,0.f,0.f,0.f}};
            const float* xp = Xs + ((size_t)arow*Tt + t)*Dd + khi;
            #pragma unroll
            for (int kb = 0; kb < KGATE/32; ++kb){
                bf16x8 a;
                if (kb < 4) a = load_x_frag(xp + kb*32);
                else        a = *reinterpret_cast<const bf16x8*>(
                                  A.hbf + (size_t)arow*Hh + (kb*32 + khi - Dd));
                #pragma unroll
                for (int fj = 0; fj < 4; ++fj){
                    bf16x8 b = *reinterpret_cast<const bf16x8*>(Wlds + ((size_t)(kb*4 + fj))*512 + lane*8);
                    ac[fj] = __builtin_amdgcn_mfma_f32_16x16x32_bf16(a, b, ac[fj], 0, 0, 0);
                }
            }
            #pragma unroll
            for (int fj = 0; fj < 4; ++fj)
            #pragma unroll
            for (int r = 0; r < 4; ++r){
                int lrow = wave*16 + ((lane >> 4) << 2) + r;
                int col  = cfo*64 + fj*16 + r15;
                size_t idx = (size_t)(grow0 + lrow)*Hh + col;
                A.fo_f[(size_t)fu*BH + idx] = sigmoidf_(ac[fj][r] + biasA0[fj]);
            }
        }

        group_barrier(ctr, (uint32_t)(128*t + 64));

        // ================= phase B: W_a GEMMs + blend + cell update =================
        if (wave < 3){
            f32x4 acB[2] = {{0.f,0.f,0.f,0.f},{0.f,0.f,0.f,0.f}};
            const ushort_t* lp = A.l_bf + (size_t)wave*BH
                               + (size_t)(grow0 + rs*16 + r15)*Hh + khi;
            #pragma unroll
            for (int kb = 0; kb < Hh/32; ++kb){
                bf16x8 a = *reinterpret_cast<const bf16x8*>(lp + kb*32);
                #pragma unroll
                for (int fj = 0; fj < 2; ++fj){
                    bf16x8 b = *reinterpret_cast<const bf16x8*>(WaLds + ((size_t)(kb*2 + fj))*512 + lane*8);
                    acB[fj] = __builtin_amdgcn_mfma_f32_16x16x32_bf16(a, b, acB[fj], 0, 0, 0);
                }
            }
            #pragma unroll
            for (int fj = 0; fj < 2; ++fj)
            #pragma unroll
            for (int r = 0; r < 4; ++r){
                int rowL = ((lane >> 4) << 2) + r;
                int colL = fj*16 + r15;
                u_lds[(wave*16 + rowL)*33 + colL] = acB[fj][r];
            }
        }
        __syncthreads();

        {   // elementwise: 2 elements per thread; c lives in registers
            #pragma unroll
            for (int e = 0; e < 2; ++e){
                int rowX = rowE + e*8;
                int growX = e ? growE1 : growE0;
                float cv = e ? creg1 : creg0;
                size_t gidx = (size_t)growX*Hh + gcol;
                float u0 = u_lds[(0*16 + rowX)*33 + colE];
                float u1 = u_lds[(1*16 + rowX)*33 + colE];
                float u2 = u_lds[(2*16 + rowX)*33 + colE];
                float e0 = __expf(tanhf_(u0*cv + ba));
                float e1 = __expf(tanhf_(u1*cv + ba));
                float e2 = __expf(tanhf_(u2*cv + ba));
                float inv = 1.f/(e0 + e1 + e2);
                float l0 = A.l_f[gidx];
                float l1 = A.l_f[(size_t)BH + gidx];
                float l2 = A.l_f[(size_t)2*BH + gidx];
                float fg = A.fo_f[gidx];
                float og = A.fo_f[(size_t)BH + gidx];
                float L = (e0*l0 + e1*l1 + e2*l2)*inv;
                float cn = fg*cv + L;
                float hn = og*tanhf_(cn);
                if (e) creg1 = cn; else creg0 = cn;
                A.hbf[gidx] = f2bf(hn);
                A.out[(size_t)BH + ((size_t)growX*Tt + t)*Hh + gcol] = hn;
                if (t == Tt - 1) A.out[gidx] = hn;
            }
        }

        if (t != Tt - 1) group_barrier(ctr, (uint32_t)(128*t + 128));
    }
}

extern "C" void kernel_launch(void* const* d_in, const int* in_sizes, int n_in,
                              void* d_out, int out_size, void* d_ws, size_t ws_size,
                              hipStream_t stream){
    const float* in[29];
    for (int i = 0; i < 29; ++i) in[i] = (const float*)d_in[i];

    char* ws = (char*)d_ws;
    ushort_t* wpack = (ushort_t*)(ws + 0);         // 9*MATSZ*2 = 5,898,240 B
    ushort_t* hbf   = (ushort_t*)(ws + 5898240);   //   262,144 B
    ushort_t* l_bf  = (ushort_t*)(ws + 6160384);   //   786,432 B
    float*    l_f   = (float*)   (ws + 6946816);   // 1,572,864 B
    float*    fo_f  = (float*)   (ws + 8519680);   // 1,048,576 B
    uint32_t* bar   = (uint32_t*)(ws + 9568256);   //        32 B
    // total ~9.57 MB of d_ws

    // mats: 0:i 1:i_p 2:i_n 3:f 4:c 5:c_p 6:c_n 7:o (K=640, [W;U]) ; 8: W_a (K=512)
    static const int WI[9] = {0, 3, 6, 9, 12, 15, 18, 21, 24};
    static const int UI[9] = {1, 4, 7, 10, 13, 16, 19, 22, -1};
    for (int m = 0; m < 9; ++m){
        int Ktot = (m == 8) ? Hh : KGATE;
        const float* Um = (m == 8) ? nullptr : in[UI[m]];
        int groups = Ktot*64;
        pack_mat<<<dim3((groups + 255)/256), dim3(256), 0, stream>>>(
            in[WI[m]], Um, Ktot, wpack + (size_t)m*MATSZ);
    }
    init_state2<<<dim3(BH/256), dim3(256), 0, stream>>>(hbf, bar);

    PK pk;
    pk.wpack = wpack;
    pk.X0 = in[26]; pk.X1 = in[27]; pk.X2 = in[28];
    pk.bC0 = in[14]; pk.bC1 = in[17]; pk.bC2 = in[20];
    pk.bI0 = in[2];  pk.bI1 = in[5];  pk.bI2 = in[8];
    pk.bF = in[11]; pk.bO = in[23]; pk.b_a = in[25];
    pk.hbf = hbf; pk.l_bf = l_bf; pk.l_f = l_f; pk.fo_f = fo_f;
    pk.bar = bar; pk.out = (float*)d_out;

    hipFuncSetAttribute((const void*)lstm_persistent,
                        hipFuncAttributeMaxDynamicSharedMemorySize, LDSB);
    void* args[] = { &pk };
    hipLaunchCooperativeKernel((const void*)lstm_persistent,
                               dim3(256), dim3(256), args, LDSB, stream);
}

// Round 4
// 37421.924 us; speedup vs baseline: 1.0961x; 1.0961x over previous
//
#include <hip/hip_runtime.h>
#include <cstdint>

#define Bb 256
#define Tt 512
#define Dd 128
#define Hh 512
#define BH (Bb*Hh)            // 131072
#define KGATE 640
#define NCT (Hh/16)           // 32 col-tiles per matrix
#define MATSZ (KGATE*Hh)      // 327680 elements per gate matrix slot
#define LDSB (81920 + 32768 + 3*16*33*4)   // weights + W_a slice + u_lds = 121024 B

typedef unsigned short ushort_t;
typedef __bf16 bf16x8 __attribute__((ext_vector_type(8)));
typedef unsigned short u16x8 __attribute__((ext_vector_type(8)));
typedef float f32x4 __attribute__((ext_vector_type(4)));

static __device__ inline ushort_t f2bf(float f){
    union { float f; uint32_t u; } v; v.f = f;
    uint32_t u = v.u;
    uint32_t r = (u + 0x7FFFu + ((u >> 16) & 1u)) >> 16;
    return (ushort_t)r;
}
static __device__ inline float sigmoidf_(float x){ return 1.f/(1.f+__expf(-x)); }
static __device__ inline float tanhf_(float x){
    float ax = fabsf(x);
    float t = __expf(-2.f*ax);
    float r = (1.f - t)/(1.f + t);
    return copysignf(r, x);
}
static __device__ inline bf16x8 load_x_frag(const float* xp){
    f32x4 v0 = *reinterpret_cast<const f32x4*>(xp);
    f32x4 v1 = *reinterpret_cast<const f32x4*>(xp + 4);
    u16x8 tmp;
    #pragma unroll
    for (int j = 0; j < 4; ++j){ tmp[j] = f2bf(v0[j]); tmp[4+j] = f2bf(v1[j]); }
    return __builtin_bit_cast(bf16x8, tmp);
}

// Pack one weight matrix (optionally stacked [W(128 rows); U(512 rows)]) into
// MFMA B-fragment order: elem(lane,j) = M[kb*32 + (lane>>4)*8 + j][ct*16 + (lane&15)]
__global__ void pack_mat(const float* __restrict__ Wm, const float* __restrict__ Um,
                         int Ktot, ushort_t* __restrict__ dst){
    int total = Ktot * 64;  // groups of 8 bf16
    for (int g = blockIdx.x*blockDim.x + threadIdx.x; g < total; g += gridDim.x*blockDim.x){
        int kb   = g >> 11;
        int rem  = g & 2047;
        int ct   = rem >> 6;
        int lane = rem & 63;
        int k0   = kb*32 + ((lane >> 4) << 3);
        int col  = (ct << 4) + (lane & 15);
        u16x8 o8;
        #pragma unroll
        for (int j = 0; j < 8; ++j){
            int k = k0 + j;
            float v;
            if (Um) v = (k < Dd) ? Wm[k*Hh + col] : Um[(k - Dd)*Hh + col];
            else    v = Wm[k*Hh + col];
            o8[j] = f2bf(v);
        }
        *reinterpret_cast<u16x8*>(dst + (size_t)g*8) = o8;
    }
}

__global__ void init_state2(ushort_t* hbf, uint32_t* bar){
    int i = blockIdx.x*blockDim.x + threadIdx.x;
    if (i < BH) hbf[i] = 0;
    if (i < 256) bar[i] = 0;   // 4 groups x 64 block-flags
}

struct PK {
    const ushort_t* wpack;
    const float* X0; const float* X1; const float* X2;
    const float* bC0; const float* bC1; const float* bC2;
    const float* bI0; const float* bI1; const float* bI2;
    const float* bF; const float* bO; const float* b_a;
    ushort_t* hbf; ushort_t* l_bf; float* l_f; float* fo_f;
    uint32_t* bar; float* out;
};

// Contention-free group barrier: each block publishes its own flag slot
// (relaxed store after a release fence), wave 0 polls all 64 slots with
// relaxed loads, then everyone does one acquire fence.
static __device__ inline void group_barrier(uint32_t* gflags, int gb, uint32_t val){
    __builtin_amdgcn_fence(__ATOMIC_RELEASE, "agent");
    __syncthreads();
    if (threadIdx.x == 0)
        __hip_atomic_store(&gflags[gb], val, __ATOMIC_RELAXED, __HIP_MEMORY_SCOPE_AGENT);
    if (threadIdx.x < 64){
        while (__hip_atomic_load(&gflags[threadIdx.x], __ATOMIC_RELAXED,
                                 __HIP_MEMORY_SCOPE_AGENT) < val)
            __builtin_amdgcn_s_sleep(2);
    }
    __syncthreads();
    __builtin_amdgcn_fence(__ATOMIC_ACQUIRE, "agent");
}

// 256 blocks x 256 threads, cooperative. Group g = bid>>6 owns batch rows [g*64, g*64+64).
// Within a group (gb = bid&63):
//   gb 0..47 : paired gate blocks  (stream s=gb>>4, col-slice cs=gb&15, 32 cols): c-mat + i-mat
//   gb 48..55: f-gate block (col-slice 64 wide)
//   gb 56..63: o-gate block (col-slice 64 wide)
// Phase B (all blocks): rows rs*16 (rs=gb>>4), cols c2*32 (c2=gb&15), c state in registers.
__global__ __launch_bounds__(256, 1) void lstm_persistent(PK A){
    extern __shared__ char lds[];
    ushort_t* Wlds  = (ushort_t*)lds;                    // 81920 B
    ushort_t* WaLds = (ushort_t*)(lds + 81920);          // 32768 B
    float*    u_lds = (float*)(lds + 81920 + 32768);     // 3*16*33 f32

    const int bid = blockIdx.x;
    const int g   = bid >> 6;
    const int gb  = bid & 63;
    const int tid = threadIdx.x;
    const int lane = tid & 63;
    const int wave = tid >> 6;
    const int r15  = lane & 15;
    const int khi  = (lane >> 4) << 3;
    const int grow0 = g << 6;

    const bool paired = (gb < 48);
    const int s   = gb >> 4;          // stream (valid when paired)
    const int cs  = gb & 15;          // 32-wide col slice (paired)
    const int fu  = (gb >= 56) ? 1 : 0;
    const int cfo = (gb - 48) & 7;    // 64-wide col slice (f/o)

    // ---- stage weights into LDS (once) ----
    if (paired){
        const ushort_t* base0 = A.wpack + (size_t)(4 + s)*MATSZ;  // c-mat
        const ushort_t* base1 = A.wpack + (size_t)s*MATSZ;        // i-mat
        for (int u = tid; u < 80*64; u += 256){
            int ch = u >> 6, un = u & 63;
            int m2 = (ch >= 40) ? 1 : 0;
            int rem = ch - m2*40;
            int kb = rem >> 1, j = rem & 1;
            const ushort_t* src = (m2 == 0 ? base0 : base1)
                                + ((size_t)(kb*NCT + cs*2 + j)*64 + un)*8;
            *reinterpret_cast<u16x8*>(Wlds + ((size_t)ch*64 + un)*8)
                = *reinterpret_cast<const u16x8*>(src);
        }
    } else {
        const ushort_t* base = A.wpack + (size_t)(fu == 0 ? 3 : 7)*MATSZ;
        for (int u = tid; u < 80*64; u += 256){
            int ch = u >> 6, un = u & 63;
            int kb = ch >> 2, j = ch & 3;
            const ushort_t* src = base + ((size_t)(kb*NCT + cfo*4 + j)*64 + un)*8;
            *reinterpret_cast<u16x8*>(Wlds + ((size_t)ch*64 + un)*8)
                = *reinterpret_cast<const u16x8*>(src);
        }
    }
    const int rs = gb >> 4, c2 = gb & 15;   // phase-B tile
    {
        const ushort_t* base = A.wpack + (size_t)8*MATSZ;
        for (int u = tid; u < 32*64; u += 256){
            int ch = u >> 6, un = u & 63;
            int kb = ch >> 1, j = ch & 1;
            const ushort_t* src = base + ((size_t)(kb*NCT + c2*2 + j)*64 + un)*8;
            *reinterpret_cast<u16x8*>(WaLds + ((size_t)ch*64 + un)*8)
                = *reinterpret_cast<const u16x8*>(src);
        }
    }
    __syncthreads();

    // ---- per-thread persistent state ----
    float biasA0[4] = {0,0,0,0}, biasA1[2] = {0,0};
    if (paired){
        const float* bCs = (s == 0) ? A.bC0 : (s == 1) ? A.bC1 : A.bC2;
        const float* bIs = (s == 0) ? A.bI0 : (s == 1) ? A.bI1 : A.bI2;
        #pragma unroll
        for (int fj = 0; fj < 2; ++fj){
            int col = cs*32 + fj*16 + r15;
            biasA0[fj] = bCs[col];
            biasA1[fj] = bIs[col];
        }
    } else {
        const float* bb = fu ? A.bO : A.bF;
        #pragma unroll
        for (int fj = 0; fj < 4; ++fj)
            biasA0[fj] = bb[cfo*64 + fj*16 + r15];
    }
    const int rowE = tid >> 5;          // 0..7
    const int colE = tid & 31;
    const int gcol = c2*32 + colE;
    const int growE0 = grow0 + rs*16 + rowE;
    const int growE1 = growE0 + 8;
    const float ba = A.b_a[gcol];
    float creg0 = 0.f, creg1 = 0.f;

    const float* Xs = paired ? ((s == 0) ? A.X0 : (s == 1) ? A.X1 : A.X2) : A.X0;
    uint32_t* gflags = A.bar + g*64;
    const int arow = grow0 + wave*16 + r15;      // phase-A A-frag row (global batch row)

    for (int t = 0; t < Tt; ++t){
        // ================= phase A: gate GEMMs =================
        if (paired){
            f32x4 a0[2] = {{0.f,0.f,0.f,0.f},{0.f,0.f,0.f,0.f}};
            f32x4 a1[2] = {{0.f,0.f,0.f,0.f},{0.f,0.f,0.f,0.f}};
            const float* xp = Xs + ((size_t)arow*Tt + t)*Dd + khi;
            #pragma unroll
            for (int kb = 0; kb < KGATE/32; ++kb){
                bf16x8 a;
                if (kb < 4) a = load_x_frag(xp + kb*32);
                else        a = *reinterpret_cast<const bf16x8*>(
                                  A.hbf + (size_t)arow*Hh + (kb*32 + khi - Dd));
                #pragma unroll
                for (int fj = 0; fj < 2; ++fj){
                    bf16x8 b0 = *reinterpret_cast<const bf16x8*>(Wlds + ((size_t)(kb*2 + fj))*512 + lane*8);
                    a0[fj] = __builtin_amdgcn_mfma_f32_16x16x32_bf16(a, b0, a0[fj], 0, 0, 0);
                    bf16x8 b1 = *reinterpret_cast<const bf16x8*>(Wlds + ((size_t)((20 + kb)*2 + fj))*512 + lane*8);
                    a1[fj] = __builtin_amdgcn_mfma_f32_16x16x32_bf16(a, b1, a1[fj], 0, 0, 0);
                }
            }
            #pragma unroll
            for (int fj = 0; fj < 2; ++fj)
            #pragma unroll
            for (int r = 0; r < 4; ++r){
                int lrow = wave*16 + ((lane >> 4) << 2) + r;
                int col  = cs*32 + fj*16 + r15;
                size_t idx = (size_t)(grow0 + lrow)*Hh + col;
                float l = tanhf_(a0[fj][r] + biasA0[fj]) * sigmoidf_(a1[fj][r] + biasA1[fj]);
                __builtin_nontemporal_store(l, &A.l_f[(size_t)s*BH + idx]);
                __builtin_nontemporal_store(f2bf(l), &A.l_bf[(size_t)s*BH + idx]);
            }
        } else {
            f32x4 ac[4] = {{0.f,0.f,0.f,0.f},{0.f,0.f,0.f,0.f},{0.f,0.f,0.f,0.f},{0.f,0.f,0.f,0.f}};
            const float* xp = Xs + ((size_t)arow*Tt + t)*Dd + khi;
            #pragma unroll
            for (int kb = 0; kb < KGATE/32; ++kb){
                bf16x8 a;
                if (kb < 4) a = load_x_frag(xp + kb*32);
                else        a = *reinterpret_cast<const bf16x8*>(
                                  A.hbf + (size_t)arow*Hh + (kb*32 + khi - Dd));
                #pragma unroll
                for (int fj = 0; fj < 4; ++fj){
                    bf16x8 b = *reinterpret_cast<const bf16x8*>(Wlds + ((size_t)(kb*4 + fj))*512 + lane*8);
                    ac[fj] = __builtin_amdgcn_mfma_f32_16x16x32_bf16(a, b, ac[fj], 0, 0, 0);
                }
            }
            #pragma unroll
            for (int fj = 0; fj < 4; ++fj)
            #pragma unroll
            for (int r = 0; r < 4; ++r){
                int lrow = wave*16 + ((lane >> 4) << 2) + r;
                int col  = cfo*64 + fj*16 + r15;
                size_t idx = (size_t)(grow0 + lrow)*Hh + col;
                __builtin_nontemporal_store(sigmoidf_(ac[fj][r] + biasA0[fj]),
                                            &A.fo_f[(size_t)fu*BH + idx]);
            }
        }

        group_barrier(gflags, gb, (uint32_t)(2*t + 1));

        // ================= phase B: W_a GEMMs + blend + cell update =================
        if (wave < 3){
            f32x4 acB[2] = {{0.f,0.f,0.f,0.f},{0.f,0.f,0.f,0.f}};
            const ushort_t* lp = A.l_bf + (size_t)wave*BH
                               + (size_t)(grow0 + rs*16 + r15)*Hh + khi;
            #pragma unroll
            for (int kb = 0; kb < Hh/32; ++kb){
                bf16x8 a = *reinterpret_cast<const bf16x8*>(lp + kb*32);
                #pragma unroll
                for (int fj = 0; fj < 2; ++fj){
                    bf16x8 b = *reinterpret_cast<const bf16x8*>(WaLds + ((size_t)(kb*2 + fj))*512 + lane*8);
                    acB[fj] = __builtin_amdgcn_mfma_f32_16x16x32_bf16(a, b, acB[fj], 0, 0, 0);
                }
            }
            #pragma unroll
            for (int fj = 0; fj < 2; ++fj)
            #pragma unroll
            for (int r = 0; r < 4; ++r){
                int rowL = ((lane >> 4) << 2) + r;
                int colL = fj*16 + r15;
                u_lds[(wave*16 + rowL)*33 + colL] = acB[fj][r];
            }
        }
        __syncthreads();

        {   // elementwise: 2 elements per thread; c lives in registers
            #pragma unroll
            for (int e = 0; e < 2; ++e){
                int rowX = rowE + e*8;
                int growX = e ? growE1 : growE0;
                float cv = e ? creg1 : creg0;
                size_t gidx = (size_t)growX*Hh + gcol;
                float u0 = u_lds[(0*16 + rowX)*33 + colE];
                float u1 = u_lds[(1*16 + rowX)*33 + colE];
                float u2 = u_lds[(2*16 + rowX)*33 + colE];
                float e0 = __expf(tanhf_(u0*cv + ba));
                float e1 = __expf(tanhf_(u1*cv + ba));
                float e2 = __expf(tanhf_(u2*cv + ba));
                float inv = 1.f/(e0 + e1 + e2);
                float l0 = A.l_f[gidx];
                float l1 = A.l_f[(size_t)BH + gidx];
                float l2 = A.l_f[(size_t)2*BH + gidx];
                float fg = A.fo_f[gidx];
                float og = A.fo_f[(size_t)BH + gidx];
                float L = (e0*l0 + e1*l1 + e2*l2)*inv;
                float cn = fg*cv + L;
                float hn = og*tanhf_(cn);
                if (e) creg1 = cn; else creg0 = cn;
                __builtin_nontemporal_store(f2bf(hn), &A.hbf[gidx]);
                __builtin_nontemporal_store(hn, &A.out[(size_t)BH + ((size_t)growX*Tt + t)*Hh + gcol]);
                if (t == Tt - 1) __builtin_nontemporal_store(hn, &A.out[gidx]);
            }
        }

        if (t != Tt - 1) group_barrier(gflags, gb, (uint32_t)(2*t + 2));
    }
}

extern "C" void kernel_launch(void* const* d_in, const int* in_sizes, int n_in,
                              void* d_out, int out_size, void* d_ws, size_t ws_size,
                              hipStream_t stream){
    const float* in[29];
    for (int i = 0; i < 29; ++i) in[i] = (const float*)d_in[i];

    char* ws = (char*)d_ws;
    ushort_t* wpack = (ushort_t*)(ws + 0);         // 9*MATSZ*2 = 5,898,240 B
    ushort_t* hbf   = (ushort_t*)(ws + 5898240);   //   262,144 B
    ushort_t* l_bf  = (ushort_t*)(ws + 6160384);   //   786,432 B
    float*    l_f   = (float*)   (ws + 6946816);   // 1,572,864 B
    float*    fo_f  = (float*)   (ws + 8519680);   // 1,048,576 B
    uint32_t* bar   = (uint32_t*)(ws + 9568256);   //     1,024 B
    // total ~9.57 MB of d_ws

    // mats: 0:i 1:i_p 2:i_n 3:f 4:c 5:c_p 6:c_n 7:o (K=640, [W;U]) ; 8: W_a (K=512)
    static const int WI[9] = {0, 3, 6, 9, 12, 15, 18, 21, 24};
    static const int UI[9] = {1, 4, 7, 10, 13, 16, 19, 22, -1};
    for (int m = 0; m < 9; ++m){
        int Ktot = (m == 8) ? Hh : KGATE;
        const float* Um = (m == 8) ? nullptr : in[UI[m]];
        int groups = Ktot*64;
        pack_mat<<<dim3((groups + 255)/256), dim3(256), 0, stream>>>(
            in[WI[m]], Um, Ktot, wpack + (size_t)m*MATSZ);
    }
    init_state2<<<dim3(BH/256), dim3(256), 0, stream>>>(hbf, bar);

    PK pk;
    pk.wpack = wpack;
    pk.X0 = in[26]; pk.X1 = in[27]; pk.X2 = in[28];
    pk.bC0 = in[14]; pk.bC1 = in[17]; pk.bC2 = in[20];
    pk.bI0 = in[2];  pk.bI1 = in[5];  pk.bI2 = in[8];
    pk.bF = in[11]; pk.bO = in[23]; pk.b_a = in[25];
    pk.hbf = hbf; pk.l_bf = l_bf; pk.l_f = l_f; pk.fo_f = fo_f;
    pk.bar = bar; pk.out = (float*)d_out;

    hipFuncSetAttribute((const void*)lstm_persistent,
                        hipFuncAttributeMaxDynamicSharedMemorySize, LDSB);
    void* args[] = { &pk };
    hipLaunchCooperativeKernel((const void*)lstm_persistent,
                               dim3(256), dim3(256), args, LDSB, stream);
}

// Round 5
// 13664.342 us; speedup vs baseline: 3.0019x; 2.7387x over previous
//
#include <hip/hip_runtime.h>
#include <cstdint>

#define Bb 256
#define Tt 512
#define Dd 128
#define Hh 512
#define BH (Bb*Hh)            // 131072
#define KGATE 640
#define NCT (Hh/16)           // 32 col-tiles per matrix
#define MATSZ (KGATE*Hh)      // 327680 elements per gate matrix slot
#define LDSB (81920 + 32768 + 3*16*33*4)   // weights + W_a slice + u_lds = 121024 B

typedef unsigned short ushort_t;
typedef __bf16 bf16x8 __attribute__((ext_vector_type(8)));
typedef unsigned short u16x8 __attribute__((ext_vector_type(8)));
typedef float f32x4 __attribute__((ext_vector_type(4)));

static __device__ inline ushort_t f2bf(float f){
    union { float f; uint32_t u; } v; v.f = f;
    uint32_t u = v.u;
    uint32_t r = (u + 0x7FFFu + ((u >> 16) & 1u)) >> 16;
    return (ushort_t)r;
}
static __device__ inline float sigmoidf_(float x){ return 1.f/(1.f+__expf(-x)); }
static __device__ inline float tanhf_(float x){
    float ax = fabsf(x);
    float t = __expf(-2.f*ax);
    float r = (1.f - t)/(1.f + t);
    return copysignf(r, x);
}
static __device__ inline bf16x8 load_x_frag(const float* xp){
    f32x4 v0 = *reinterpret_cast<const f32x4*>(xp);
    f32x4 v1 = *reinterpret_cast<const f32x4*>(xp + 4);
    u16x8 tmp;
    #pragma unroll
    for (int j = 0; j < 4; ++j){ tmp[j] = f2bf(v0[j]); tmp[4+j] = f2bf(v1[j]); }
    return __builtin_bit_cast(bf16x8, tmp);
}

// ---- device-coherent (agent-scope, relaxed) accessors: no fences needed ----
static __device__ inline void st_u32(uint32_t* p, uint32_t v){
    __hip_atomic_store(p, v, __ATOMIC_RELAXED, __HIP_MEMORY_SCOPE_AGENT);
}
static __device__ inline uint32_t ld_u32(const uint32_t* p){
    return __hip_atomic_load(p, __ATOMIC_RELAXED, __HIP_MEMORY_SCOPE_AGENT);
}
static __device__ inline void st_f32(float* p, float v){
    __hip_atomic_store(p, v, __ATOMIC_RELAXED, __HIP_MEMORY_SCOPE_AGENT);
}
static __device__ inline float ld_f32(const float* p){
    return __hip_atomic_load(p, __ATOMIC_RELAXED, __HIP_MEMORY_SCOPE_AGENT);
}
static __device__ inline bf16x8 ld_frag32(const uint32_t* q){
    union { uint32_t w[4]; bf16x8 v; } u;
    u.w[0] = ld_u32(q + 0); u.w[1] = ld_u32(q + 1);
    u.w[2] = ld_u32(q + 2); u.w[3] = ld_u32(q + 3);
    return u.v;
}

// Pack one weight matrix (optionally stacked [W(128 rows); U(512 rows)]) into
// MFMA B-fragment order: elem(lane,j) = M[kb*32 + (lane>>4)*8 + j][ct*16 + (lane&15)]
__global__ void pack_mat(const float* __restrict__ Wm, const float* __restrict__ Um,
                         int Ktot, ushort_t* __restrict__ dst){
    int total = Ktot * 64;  // groups of 8 bf16
    for (int g = blockIdx.x*blockDim.x + threadIdx.x; g < total; g += gridDim.x*blockDim.x){
        int kb   = g >> 11;
        int rem  = g & 2047;
        int ct   = rem >> 6;
        int lane = rem & 63;
        int k0   = kb*32 + ((lane >> 4) << 3);
        int col  = (ct << 4) + (lane & 15);
        u16x8 o8;
        #pragma unroll
        for (int j = 0; j < 8; ++j){
            int k = k0 + j;
            float v;
            if (Um) v = (k < Dd) ? Wm[k*Hh + col] : Um[(k - Dd)*Hh + col];
            else    v = Wm[k*Hh + col];
            o8[j] = f2bf(v);
        }
        *reinterpret_cast<u16x8*>(dst + (size_t)g*8) = o8;
    }
}

__global__ void init_state2(ushort_t* hbf, uint32_t* bar){
    int i = blockIdx.x*blockDim.x + threadIdx.x;
    if (i < BH) hbf[i] = 0;
    if (i < 256) bar[i] = 0;   // 4 groups x 64 block-flags
}

struct PK {
    const ushort_t* wpack;
    const float* X0; const float* X1; const float* X2;
    const float* bC0; const float* bC1; const float* bC2;
    const float* bI0; const float* bI1; const float* bI2;
    const float* bF; const float* bO; const float* b_a;
    ushort_t* hbf; ushort_t* l_bf; float* l_f; float* fo_f;
    uint32_t* bar; float* out;
};

// Fence-free group barrier: all cross-block data is written with agent-scope
// relaxed atomics (device-coherent at MALL). __syncthreads drains vmcnt (the
// compiler emits s_waitcnt vmcnt(0) before s_barrier), so every block's data
// stores are globally visible before its flag publish. Workgroup-scope fences
// are compile-time ordering only (waitcnt, no cache ops).
static __device__ inline void group_barrier(uint32_t* gflags, int gb, uint32_t val){
    __builtin_amdgcn_fence(__ATOMIC_RELEASE, "workgroup");
    __syncthreads();
    if (threadIdx.x == 0) st_u32(&gflags[gb], val);
    if (threadIdx.x < 64){
        while (ld_u32(&gflags[threadIdx.x]) < val)
            __builtin_amdgcn_s_sleep(1);
    }
    __syncthreads();
    __builtin_amdgcn_fence(__ATOMIC_ACQUIRE, "workgroup");
}

// 256 blocks x 256 threads, cooperative. Group g = bid>>6 owns batch rows [g*64, g*64+64).
// Within a group (gb = bid&63):
//   gb 0..47 : paired gate blocks  (stream s=gb>>4, col-slice cs=gb&15, 32 cols): c-mat + i-mat
//   gb 48..55: f-gate block (col-slice 64 wide)
//   gb 56..63: o-gate block (col-slice 64 wide)
// Phase B (all blocks): rows rs*16 (rs=gb>>4), cols c2*32 (c2=gb&15), c state in registers.
__global__ __launch_bounds__(256, 1) void lstm_persistent(PK A){
    extern __shared__ char lds[];
    ushort_t* Wlds  = (ushort_t*)lds;                    // 81920 B
    ushort_t* WaLds = (ushort_t*)(lds + 81920);          // 32768 B
    float*    u_lds = (float*)(lds + 81920 + 32768);     // 3*16*33 f32 (also repack scratch)

    const int bid = blockIdx.x;
    const int g   = bid >> 6;
    const int gb  = bid & 63;
    const int tid = threadIdx.x;
    const int lane = tid & 63;
    const int wave = tid >> 6;
    const int r15  = lane & 15;
    const int khi  = (lane >> 4) << 3;
    const int grow0 = g << 6;

    const bool paired = (gb < 48);
    const int s   = gb >> 4;          // stream (valid when paired)
    const int cs  = gb & 15;          // 32-wide col slice (paired)
    const int fu  = (gb >= 56) ? 1 : 0;
    const int cfo = (gb - 48) & 7;    // 64-wide col slice (f/o)

    uint32_t* hbf32  = (uint32_t*)A.hbf;
    uint32_t* l_bf32 = (uint32_t*)A.l_bf;

    // ---- stage weights into LDS (once) ----
    if (paired){
        const ushort_t* base0 = A.wpack + (size_t)(4 + s)*MATSZ;  // c-mat
        const ushort_t* base1 = A.wpack + (size_t)s*MATSZ;        // i-mat
        for (int u = tid; u < 80*64; u += 256){
            int ch = u >> 6, un = u & 63;
            int m2 = (ch >= 40) ? 1 : 0;
            int rem = ch - m2*40;
            int kb = rem >> 1, j = rem & 1;
            const ushort_t* src = (m2 == 0 ? base0 : base1)
                                + ((size_t)(kb*NCT + cs*2 + j)*64 + un)*8;
            *reinterpret_cast<u16x8*>(Wlds + ((size_t)ch*64 + un)*8)
                = *reinterpret_cast<const u16x8*>(src);
        }
    } else {
        const ushort_t* base = A.wpack + (size_t)(fu == 0 ? 3 : 7)*MATSZ;
        for (int u = tid; u < 80*64; u += 256){
            int ch = u >> 6, un = u & 63;
            int kb = ch >> 2, j = ch & 3;
            const ushort_t* src = base + ((size_t)(kb*NCT + cfo*4 + j)*64 + un)*8;
            *reinterpret_cast<u16x8*>(Wlds + ((size_t)ch*64 + un)*8)
                = *reinterpret_cast<const u16x8*>(src);
        }
    }
    const int rs = gb >> 4, c2 = gb & 15;   // phase-B tile
    {
        const ushort_t* base = A.wpack + (size_t)8*MATSZ;
        for (int u = tid; u < 32*64; u += 256){
            int ch = u >> 6, un = u & 63;
            int kb = ch >> 1, j = ch & 1;
            const ushort_t* src = base + ((size_t)(kb*NCT + c2*2 + j)*64 + un)*8;
            *reinterpret_cast<u16x8*>(WaLds + ((size_t)ch*64 + un)*8)
                = *reinterpret_cast<const u16x8*>(src);
        }
    }
    __syncthreads();

    // ---- per-thread persistent state ----
    float biasA0[4] = {0,0,0,0}, biasA1[2] = {0,0};
    if (paired){
        const float* bCs = (s == 0) ? A.bC0 : (s == 1) ? A.bC1 : A.bC2;
        const float* bIs = (s == 0) ? A.bI0 : (s == 1) ? A.bI1 : A.bI2;
        #pragma unroll
        for (int fj = 0; fj < 2; ++fj){
            int col = cs*32 + fj*16 + r15;
            biasA0[fj] = bCs[col];
            biasA1[fj] = bIs[col];
        }
    } else {
        const float* bb = fu ? A.bO : A.bF;
        #pragma unroll
        for (int fj = 0; fj < 4; ++fj)
            biasA0[fj] = bb[cfo*64 + fj*16 + r15];
    }
    const int rowE = tid >> 5;          // 0..7
    const int colE = tid & 31;
    const int gcol = c2*32 + colE;
    const int growE0 = grow0 + rs*16 + rowE;
    const int growE1 = growE0 + 8;
    const float ba = A.b_a[gcol];
    float creg0 = 0.f, creg1 = 0.f;

    const float* Xs = paired ? ((s == 0) ? A.X0 : (s == 1) ? A.X1 : A.X2) : A.X0;
    uint32_t* gflags = A.bar + g*64;
    const int arow = grow0 + wave*16 + r15;      // phase-A A-frag row (global batch row)
    const uint32_t* hrow32 = hbf32 + ((size_t)arow*Hh >> 1);

    for (int t = 0; t < Tt; ++t){
        // ================= phase A: gate GEMMs =================
        if (paired){
            f32x4 a0[2] = {{0.f,0.f,0.f,0.f},{0.f,0.f,0.f,0.f}};
            f32x4 a1[2] = {{0.f,0.f,0.f,0.f},{0.f,0.f,0.f,0.f}};
            const float* xp = Xs + ((size_t)arow*Tt + t)*Dd + khi;
            #pragma unroll
            for (int kb = 0; kb < KGATE/32; ++kb){
                bf16x8 a;
                if (kb < 4) a = load_x_frag(xp + kb*32);
                else        a = ld_frag32(hrow32 + ((kb*32 + khi - Dd) >> 1));
                #pragma unroll
                for (int fj = 0; fj < 2; ++fj){
                    bf16x8 b0 = *reinterpret_cast<const bf16x8*>(Wlds + ((size_t)(kb*2 + fj))*512 + lane*8);
                    a0[fj] = __builtin_amdgcn_mfma_f32_16x16x32_bf16(a, b0, a0[fj], 0, 0, 0);
                    bf16x8 b1 = *reinterpret_cast<const bf16x8*>(Wlds + ((size_t)((20 + kb)*2 + fj))*512 + lane*8);
                    a1[fj] = __builtin_amdgcn_mfma_f32_16x16x32_bf16(a, b1, a1[fj], 0, 0, 0);
                }
            }
            ushort_t* lrep = (ushort_t*)u_lds;   // 64x32 u16 repack scratch
            #pragma unroll
            for (int fj = 0; fj < 2; ++fj)
            #pragma unroll
            for (int r = 0; r < 4; ++r){
                int lrow = wave*16 + ((lane >> 4) << 2) + r;
                int col  = cs*32 + fj*16 + r15;
                size_t idx = (size_t)(grow0 + lrow)*Hh + col;
                float l = tanhf_(a0[fj][r] + biasA0[fj]) * sigmoidf_(a1[fj][r] + biasA1[fj]);
                st_f32(&A.l_f[(size_t)s*BH + idx], l);
                lrep[lrow*32 + fj*16 + r15] = f2bf(l);
            }
            __syncthreads();
            {   // cooperative u32 stores of the bf16 tile (device-coherent)
                uint32_t* dst = l_bf32 + (((size_t)s*BH + (size_t)grow0*Hh) >> 1) + cs*16;
                const uint32_t* src = (const uint32_t*)lrep;
                #pragma unroll
                for (int k2 = 0; k2 < 4; ++k2){
                    int idx = tid + k2*256;          // 0..1023
                    int lrow = idx >> 4, cp = idx & 15;
                    st_u32(dst + (size_t)lrow*(Hh/2) + cp, src[idx]);
                }
            }
        } else {
            f32x4 ac[4] = {{0.f,0.f,0.f,0.f},{0.f,0.f,0.f,0.f},{0.f,0.f,0.f,0.f},{0.f,0.f,0.f,0.f}};
            const float* xp = Xs + ((size_t)arow*Tt + t)*Dd + khi;
            #pragma unroll
            for (int kb = 0; kb < KGATE/32; ++kb){
                bf16x8 a;
                if (kb < 4) a = load_x_frag(xp + kb*32);
                else        a = ld_frag32(hrow32 + ((kb*32 + khi - Dd) >> 1));
                #pragma unroll
                for (int fj = 0; fj < 4; ++fj){
                    bf16x8 b = *reinterpret_cast<const bf16x8*>(Wlds + ((size_t)(kb*4 + fj))*512 + lane*8);
                    ac[fj] = __builtin_amdgcn_mfma_f32_16x16x32_bf16(a, b, ac[fj], 0, 0, 0);
                }
            }
            #pragma unroll
            for (int fj = 0; fj < 4; ++fj)
            #pragma unroll
            for (int r = 0; r < 4; ++r){
                int lrow = wave*16 + ((lane >> 4) << 2) + r;
                int col  = cfo*64 + fj*16 + r15;
                size_t idx = (size_t)(grow0 + lrow)*Hh + col;
                st_f32(&A.fo_f[(size_t)fu*BH + idx], sigmoidf_(ac[fj][r] + biasA0[fj]));
            }
        }

        group_barrier(gflags, gb, (uint32_t)(2*t + 1));

        // ================= phase B: W_a GEMMs + blend + cell update =================
        if (wave < 3){
            f32x4 acB[2] = {{0.f,0.f,0.f,0.f},{0.f,0.f,0.f,0.f}};
            const uint32_t* lp32 = l_bf32 + (((size_t)wave*BH
                                 + (size_t)(grow0 + rs*16 + r15)*Hh + khi) >> 1);
            #pragma unroll
            for (int kb = 0; kb < Hh/32; ++kb){
                bf16x8 a = ld_frag32(lp32 + kb*16);
                #pragma unroll
                for (int fj = 0; fj < 2; ++fj){
                    bf16x8 b = *reinterpret_cast<const bf16x8*>(WaLds + ((size_t)(kb*2 + fj))*512 + lane*8);
                    acB[fj] = __builtin_amdgcn_mfma_f32_16x16x32_bf16(a, b, acB[fj], 0, 0, 0);
                }
            }
            #pragma unroll
            for (int fj = 0; fj < 2; ++fj)
            #pragma unroll
            for (int r = 0; r < 4; ++r){
                int rowL = ((lane >> 4) << 2) + r;
                int colL = fj*16 + r15;
                u_lds[(wave*16 + rowL)*33 + colL] = acB[fj][r];
            }
        }
        __syncthreads();

        float hn0, hn1;
        {   // elementwise: 2 elements per thread; c lives in registers
            #pragma unroll
            for (int e = 0; e < 2; ++e){
                int rowX = rowE + e*8;
                int growX = e ? growE1 : growE0;
                float cv = e ? creg1 : creg0;
                size_t gidx = (size_t)growX*Hh + gcol;
                float u0 = u_lds[(0*16 + rowX)*33 + colE];
                float u1 = u_lds[(1*16 + rowX)*33 + colE];
                float u2 = u_lds[(2*16 + rowX)*33 + colE];
                float e0 = __expf(tanhf_(u0*cv + ba));
                float e1 = __expf(tanhf_(u1*cv + ba));
                float e2 = __expf(tanhf_(u2*cv + ba));
                float inv = 1.f/(e0 + e1 + e2);
                float l0 = ld_f32(&A.l_f[gidx]);
                float l1 = ld_f32(&A.l_f[(size_t)BH + gidx]);
                float l2 = ld_f32(&A.l_f[(size_t)2*BH + gidx]);
                float fg = ld_f32(&A.fo_f[gidx]);
                float og = ld_f32(&A.fo_f[(size_t)BH + gidx]);
                float L = (e0*l0 + e1*l1 + e2*l2)*inv;
                float cn = fg*cv + L;
                float hn = og*tanhf_(cn);
                if (e) creg1 = cn; else creg0 = cn;
                __builtin_nontemporal_store(hn, &A.out[(size_t)BH + ((size_t)growX*Tt + t)*Hh + gcol]);
                if (t == Tt - 1) __builtin_nontemporal_store(hn, &A.out[gidx]);
                if (e) hn1 = hn; else hn0 = hn;
            }
        }
        __syncthreads();                       // everyone done reading u_lds
        {   // repack h tile to bf16 and store device-coherent u32s
            ushort_t* hrep = (ushort_t*)u_lds;  // 16x32 u16
            hrep[rowE*32 + colE]      = f2bf(hn0);
            hrep[(rowE+8)*32 + colE]  = f2bf(hn1);
            __syncthreads();
            uint32_t* dst = hbf32 + (((size_t)(grow0 + rs*16)*Hh) >> 1) + c2*16;
            int lr = tid >> 4, cp = tid & 15;
            st_u32(dst + (size_t)lr*(Hh/2) + cp, ((const uint32_t*)hrep)[tid]);
        }

        if (t != Tt - 1) group_barrier(gflags, gb, (uint32_t)(2*t + 2));
    }
}

extern "C" void kernel_launch(void* const* d_in, const int* in_sizes, int n_in,
                              void* d_out, int out_size, void* d_ws, size_t ws_size,
                              hipStream_t stream){
    const float* in[29];
    for (int i = 0; i < 29; ++i) in[i] = (const float*)d_in[i];

    char* ws = (char*)d_ws;
    ushort_t* wpack = (ushort_t*)(ws + 0);         // 9*MATSZ*2 = 5,898,240 B
    ushort_t* hbf   = (ushort_t*)(ws + 5898240);   //   262,144 B
    ushort_t* l_bf  = (ushort_t*)(ws + 6160384);   //   786,432 B
    float*    l_f   = (float*)   (ws + 6946816);   // 1,572,864 B
    float*    fo_f  = (float*)   (ws + 8519680);   // 1,048,576 B
    uint32_t* bar   = (uint32_t*)(ws + 9568256);   //     1,024 B
    // total ~9.57 MB of d_ws

    // mats: 0:i 1:i_p 2:i_n 3:f 4:c 5:c_p 6:c_n 7:o (K=640, [W;U]) ; 8: W_a (K=512)
    static const int WI[9] = {0, 3, 6, 9, 12, 15, 18, 21, 24};
    static const int UI[9] = {1, 4, 7, 10, 13, 16, 19, 22, -1};
    for (int m = 0; m < 9; ++m){
        int Ktot = (m == 8) ? Hh : KGATE;
        const float* Um = (m == 8) ? nullptr : in[UI[m]];
        int groups = Ktot*64;
        pack_mat<<<dim3((groups + 255)/256), dim3(256), 0, stream>>>(
            in[WI[m]], Um, Ktot, wpack + (size_t)m*MATSZ);
    }
    init_state2<<<dim3(BH/256), dim3(256), 0, stream>>>(hbf, bar);

    PK pk;
    pk.wpack = wpack;
    pk.X0 = in[26]; pk.X1 = in[27]; pk.X2 = in[28];
    pk.bC0 = in[14]; pk.bC1 = in[17]; pk.bC2 = in[20];
    pk.bI0 = in[2];  pk.bI1 = in[5];  pk.bI2 = in[8];
    pk.bF = in[11]; pk.bO = in[23]; pk.b_a = in[25];
    pk.hbf = hbf; pk.l_bf = l_bf; pk.l_f = l_f; pk.fo_f = fo_f;
    pk.bar = bar; pk.out = (float*)d_out;

    hipFuncSetAttribute((const void*)lstm_persistent,
                        hipFuncAttributeMaxDynamicSharedMemorySize, LDSB);
    void* args[] = { &pk };
    hipLaunchCooperativeKernel((const void*)lstm_persistent,
                               dim3(256), dim3(256), args, LDSB, stream);
}

// Round 6
// 11863.016 us; speedup vs baseline: 3.4578x; 1.1518x over previous
//
#include <hip/hip_runtime.h>
#include <cstdint>

#define Bb 256
#define Tt 512
#define Dd 128
#define Hh 512
#define BH (Bb*Hh)            // 131072
#define KGATE 640
#define NCT (Hh/16)           // 32 col-tiles per matrix
#define MATSZ (KGATE*Hh)      // 327680 elements per gate matrix slot
#define LDSB (81920 + 32768 + 3*16*33*4)   // weights + W_a slice + u_lds = 121024 B

typedef unsigned short ushort_t;
typedef __bf16 bf16x8 __attribute__((ext_vector_type(8)));
typedef unsigned short u16x8 __attribute__((ext_vector_type(8)));
typedef float f32x4 __attribute__((ext_vector_type(4)));

static __device__ inline ushort_t f2bf(float f){
    union { float f; uint32_t u; } v; v.f = f;
    uint32_t u = v.u;
    uint32_t r = (u + 0x7FFFu + ((u >> 16) & 1u)) >> 16;
    return (ushort_t)r;
}
static __device__ inline float sigmoidf_(float x){ return 1.f/(1.f+__expf(-x)); }
static __device__ inline float tanhf_(float x){
    float ax = fabsf(x);
    float t = __expf(-2.f*ax);
    float r = (1.f - t)/(1.f + t);
    return copysignf(r, x);
}
static __device__ inline bf16x8 load_x_frag(const float* xp){
    f32x4 v0 = *reinterpret_cast<const f32x4*>(xp);
    f32x4 v1 = *reinterpret_cast<const f32x4*>(xp + 4);
    u16x8 tmp;
    #pragma unroll
    for (int j = 0; j < 4; ++j){ tmp[j] = f2bf(v0[j]); tmp[4+j] = f2bf(v1[j]); }
    return __builtin_bit_cast(bf16x8, tmp);
}

// ---- device-coherent (agent-scope, relaxed) accessors: producers write-through ----
static __device__ inline void st_u32(uint32_t* p, uint32_t v){
    __hip_atomic_store(p, v, __ATOMIC_RELAXED, __HIP_MEMORY_SCOPE_AGENT);
}
static __device__ inline uint32_t ld_u32(const uint32_t* p){
    return __hip_atomic_load(p, __ATOMIC_RELAXED, __HIP_MEMORY_SCOPE_AGENT);
}
static __device__ inline void st_f32(float* p, float v){
    __hip_atomic_store(p, v, __ATOMIC_RELAXED, __HIP_MEMORY_SCOPE_AGENT);
}

// Pack one weight matrix (optionally stacked [W(128 rows); U(512 rows)]) into
// MFMA B-fragment order: elem(lane,j) = M[kb*32 + (lane>>4)*8 + j][ct*16 + (lane&15)]
__global__ void pack_mat(const float* __restrict__ Wm, const float* __restrict__ Um,
                         int Ktot, ushort_t* __restrict__ dst){
    int total = Ktot * 64;  // groups of 8 bf16
    for (int g = blockIdx.x*blockDim.x + threadIdx.x; g < total; g += gridDim.x*blockDim.x){
        int kb   = g >> 11;
        int rem  = g & 2047;
        int ct   = rem >> 6;
        int lane = rem & 63;
        int k0   = kb*32 + ((lane >> 4) << 3);
        int col  = (ct << 4) + (lane & 15);
        u16x8 o8;
        #pragma unroll
        for (int j = 0; j < 8; ++j){
            int k = k0 + j;
            float v;
            if (Um) v = (k < Dd) ? Wm[k*Hh + col] : Um[(k - Dd)*Hh + col];
            else    v = Wm[k*Hh + col];
            o8[j] = f2bf(v);
        }
        *reinterpret_cast<u16x8*>(dst + (size_t)g*8) = o8;
    }
}

__global__ void init_state2(ushort_t* hbf, uint32_t* bar){
    int i = blockIdx.x*blockDim.x + threadIdx.x;
    if (i < BH) hbf[i] = 0;
    if (i < 8192) bar[i] = 0;   // 4 groups x 64 block-flags x 32 u32 padding
}

struct PK {
    const ushort_t* wpack;
    const float* X0; const float* X1; const float* X2;
    const float* bC0; const float* bC1; const float* bC2;
    const float* bI0; const float* bI1; const float* bI2;
    const float* bF; const float* bO; const float* b_a;
    ushort_t* hbf;    // chunked: [16 col-chunk][256 rows][32 cols] bf16
    ushort_t* l_bf;   // chunked: [3 s][16 cs][256 rows][32 cols] bf16
    float* l_f;       // row-major [3][256][512]
    float* fo_f;      // row-major [2][256][512]
    uint32_t* bar; float* out;
};

// Contention-free group barrier: flags padded to 128B (one cacheline each — no
// false sharing between 64 producers and 64 pollers). Producers' data went out
// via agent-scope write-through stores, drained by the vmcnt(0) the compiler
// emits before s_barrier. Consumers end with an agent acquire fence (L1+L2
// invalidate) so subsequent PLAIN cached loads observe fresh MALL data.
static __device__ inline void group_barrier(uint32_t* gflags, int gb, uint32_t val){
    __builtin_amdgcn_fence(__ATOMIC_RELEASE, "workgroup");
    __syncthreads();
    if (threadIdx.x == 0) st_u32(&gflags[gb*32], val);
    if (threadIdx.x < 64){
        while (ld_u32(&gflags[threadIdx.x*32]) < val)
            __builtin_amdgcn_s_sleep(1);
    }
    __syncthreads();
    __builtin_amdgcn_fence(__ATOMIC_ACQUIRE, "agent");
}

// 256 blocks x 256 threads, cooperative. Group g = bid>>6 owns batch rows [g*64, g*64+64).
// Within a group (gb = bid&63):
//   gb 0..47 : paired gate blocks  (stream s=gb>>4, col-slice cs=gb&15, 32 cols): c-mat + i-mat
//   gb 48..55: f-gate block (col-slice 64 wide)
//   gb 56..63: o-gate block (col-slice 64 wide)
// Phase B (all blocks): rows rs*16 (rs=gb>>4), cols c2*32 (c2=gb&15), c state in registers.
__global__ __launch_bounds__(256, 1) void lstm_persistent(PK A){
    extern __shared__ char lds[];
    ushort_t* Wlds  = (ushort_t*)lds;                    // 81920 B
    ushort_t* WaLds = (ushort_t*)(lds + 81920);          // 32768 B
    float*    u_lds = (float*)(lds + 81920 + 32768);     // 3*16*33 f32 (also repack scratch)

    const int bid = blockIdx.x;
    const int g   = bid >> 6;
    const int gb  = bid & 63;
    const int tid = threadIdx.x;
    const int lane = tid & 63;
    const int wave = tid >> 6;
    const int r15  = lane & 15;
    const int khi  = (lane >> 4) << 3;
    const int grow0 = g << 6;

    const bool paired = (gb < 48);
    const int s   = gb >> 4;          // stream (valid when paired)
    const int cs  = gb & 15;          // 32-wide col slice (paired)
    const int fu  = (gb >= 56) ? 1 : 0;
    const int cfo = (gb - 48) & 7;    // 64-wide col slice (f/o)

    uint32_t* hbf32  = (uint32_t*)A.hbf;
    uint32_t* l_bf32 = (uint32_t*)A.l_bf;

    // ---- stage weights into LDS (once) ----
    if (paired){
        const ushort_t* base0 = A.wpack + (size_t)(4 + s)*MATSZ;  // c-mat
        const ushort_t* base1 = A.wpack + (size_t)s*MATSZ;        // i-mat
        for (int u = tid; u < 80*64; u += 256){
            int ch = u >> 6, un = u & 63;
            int m2 = (ch >= 40) ? 1 : 0;
            int rem = ch - m2*40;
            int kb = rem >> 1, j = rem & 1;
            const ushort_t* src = (m2 == 0 ? base0 : base1)
                                + ((size_t)(kb*NCT + cs*2 + j)*64 + un)*8;
            *reinterpret_cast<u16x8*>(Wlds + ((size_t)ch*64 + un)*8)
                = *reinterpret_cast<const u16x8*>(src);
        }
    } else {
        const ushort_t* base = A.wpack + (size_t)(fu == 0 ? 3 : 7)*MATSZ;
        for (int u = tid; u < 80*64; u += 256){
            int ch = u >> 6, un = u & 63;
            int kb = ch >> 2, j = ch & 3;
            const ushort_t* src = base + ((size_t)(kb*NCT + cfo*4 + j)*64 + un)*8;
            *reinterpret_cast<u16x8*>(Wlds + ((size_t)ch*64 + un)*8)
                = *reinterpret_cast<const u16x8*>(src);
        }
    }
    const int rs = gb >> 4, c2 = gb & 15;   // phase-B tile
    {
        const ushort_t* base = A.wpack + (size_t)8*MATSZ;
        for (int u = tid; u < 32*64; u += 256){
            int ch = u >> 6, un = u & 63;
            int kb = ch >> 1, j = ch & 1;
            const ushort_t* src = base + ((size_t)(kb*NCT + c2*2 + j)*64 + un)*8;
            *reinterpret_cast<u16x8*>(WaLds + ((size_t)ch*64 + un)*8)
                = *reinterpret_cast<const u16x8*>(src);
        }
    }
    __syncthreads();

    // ---- per-thread persistent state ----
    float biasA0[4] = {0,0,0,0}, biasA1[2] = {0,0};
    if (paired){
        const float* bCs = (s == 0) ? A.bC0 : (s == 1) ? A.bC1 : A.bC2;
        const float* bIs = (s == 0) ? A.bI0 : (s == 1) ? A.bI1 : A.bI2;
        #pragma unroll
        for (int fj = 0; fj < 2; ++fj){
            int col = cs*32 + fj*16 + r15;
            biasA0[fj] = bCs[col];
            biasA1[fj] = bIs[col];
        }
    } else {
        const float* bb = fu ? A.bO : A.bF;
        #pragma unroll
        for (int fj = 0; fj < 4; ++fj)
            biasA0[fj] = bb[cfo*64 + fj*16 + r15];
    }
    const int rowE = tid >> 5;          // 0..7
    const int colE = tid & 31;
    const int gcol = c2*32 + colE;
    const int growE0 = grow0 + rs*16 + rowE;
    const int growE1 = growE0 + 8;
    const float ba = A.b_a[gcol];
    float creg0 = 0.f, creg1 = 0.f;

    const float* Xs = paired ? ((s == 0) ? A.X0 : (s == 1) ? A.X1 : A.X2) : A.X0;
    uint32_t* gflags = A.bar + g*64*32;
    const int arow = grow0 + wave*16 + r15;      // phase-A A-frag row (global batch row)

    for (int t = 0; t < Tt; ++t){
        // ================= phase A: gate GEMMs =================
        if (paired){
            f32x4 a0[2] = {{0.f,0.f,0.f,0.f},{0.f,0.f,0.f,0.f}};
            f32x4 a1[2] = {{0.f,0.f,0.f,0.f},{0.f,0.f,0.f,0.f}};
            const float* xp = Xs + ((size_t)arow*Tt + t)*Dd + khi;
            #pragma unroll
            for (int kb = 0; kb < KGATE/32; ++kb){
                bf16x8 a;
                if (kb < 4) a = load_x_frag(xp + kb*32);
                else        a = *reinterpret_cast<const bf16x8*>(     // chunked h: [kb-4][arow][khi]
                                  A.hbf + (((size_t)(kb-4)*Bb + arow)*32 + khi));
                #pragma unroll
                for (int fj = 0; fj < 2; ++fj){
                    bf16x8 b0 = *reinterpret_cast<const bf16x8*>(Wlds + ((size_t)(kb*2 + fj))*512 + lane*8);
                    a0[fj] = __builtin_amdgcn_mfma_f32_16x16x32_bf16(a, b0, a0[fj], 0, 0, 0);
                    bf16x8 b1 = *reinterpret_cast<const bf16x8*>(Wlds + ((size_t)((20 + kb)*2 + fj))*512 + lane*8);
                    a1[fj] = __builtin_amdgcn_mfma_f32_16x16x32_bf16(a, b1, a1[fj], 0, 0, 0);
                }
            }
            ushort_t* lrep = (ushort_t*)u_lds;   // 64x32 u16 repack scratch
            #pragma unroll
            for (int fj = 0; fj < 2; ++fj)
            #pragma unroll
            for (int r = 0; r < 4; ++r){
                int lrow = wave*16 + ((lane >> 4) << 2) + r;
                int col  = cs*32 + fj*16 + r15;
                size_t idx = (size_t)(grow0 + lrow)*Hh + col;
                float l = tanhf_(a0[fj][r] + biasA0[fj]) * sigmoidf_(a1[fj][r] + biasA1[fj]);
                st_f32(&A.l_f[(size_t)s*BH + idx], l);
                lrep[lrow*32 + fj*16 + r15] = f2bf(l);
            }
            __syncthreads();
            {   // cooperative u32 stores of the bf16 tile into block-exclusive chunk
                // chunk [s][cs]: base (s*16+cs)*256 rows; rows grow0..grow0+63; 16 u32/row
                uint32_t* dst = l_bf32 + ((size_t)(s*16 + cs)*Bb + grow0)*16;
                const uint32_t* src = (const uint32_t*)lrep;
                #pragma unroll
                for (int k2 = 0; k2 < 4; ++k2){
                    int idx = tid + k2*256;          // 0..1023
                    int lrow = idx >> 4, cp = idx & 15;
                    st_u32(dst + (size_t)lrow*16 + cp, src[idx]);
                }
            }
        } else {
            f32x4 ac[4] = {{0.f,0.f,0.f,0.f},{0.f,0.f,0.f,0.f},{0.f,0.f,0.f,0.f},{0.f,0.f,0.f,0.f}};
            const float* xp = Xs + ((size_t)arow*Tt + t)*Dd + khi;
            #pragma unroll
            for (int kb = 0; kb < KGATE/32; ++kb){
                bf16x8 a;
                if (kb < 4) a = load_x_frag(xp + kb*32);
                else        a = *reinterpret_cast<const bf16x8*>(
                                  A.hbf + (((size_t)(kb-4)*Bb + arow)*32 + khi));
                #pragma unroll
                for (int fj = 0; fj < 4; ++fj){
                    bf16x8 b = *reinterpret_cast<const bf16x8*>(Wlds + ((size_t)(kb*4 + fj))*512 + lane*8);
                    ac[fj] = __builtin_amdgcn_mfma_f32_16x16x32_bf16(a, b, ac[fj], 0, 0, 0);
                }
            }
            #pragma unroll
            for (int fj = 0; fj < 4; ++fj)
            #pragma unroll
            for (int r = 0; r < 4; ++r){
                int lrow = wave*16 + ((lane >> 4) << 2) + r;
                int col  = cfo*64 + fj*16 + r15;
                size_t idx = (size_t)(grow0 + lrow)*Hh + col;
                st_f32(&A.fo_f[(size_t)fu*BH + idx], sigmoidf_(ac[fj][r] + biasA0[fj]));
            }
        }

        group_barrier(gflags, gb, (uint32_t)(2*t + 1));

        // ================= phase B: W_a GEMMs + blend + cell update =================
        if (wave < 3){
            f32x4 acB[2] = {{0.f,0.f,0.f,0.f},{0.f,0.f,0.f,0.f}};
            const int brow = grow0 + rs*16 + r15;
            #pragma unroll
            for (int kb = 0; kb < Hh/32; ++kb){
                // chunked l_bf: [wave][kb][brow][khi]
                bf16x8 a = *reinterpret_cast<const bf16x8*>(
                    A.l_bf + (((size_t)(wave*16 + kb)*Bb + brow)*32 + khi));
                #pragma unroll
                for (int fj = 0; fj < 2; ++fj){
                    bf16x8 b = *reinterpret_cast<const bf16x8*>(WaLds + ((size_t)(kb*2 + fj))*512 + lane*8);
                    acB[fj] = __builtin_amdgcn_mfma_f32_16x16x32_bf16(a, b, acB[fj], 0, 0, 0);
                }
            }
            #pragma unroll
            for (int fj = 0; fj < 2; ++fj)
            #pragma unroll
            for (int r = 0; r < 4; ++r){
                int rowL = ((lane >> 4) << 2) + r;
                int colL = fj*16 + r15;
                u_lds[(wave*16 + rowL)*33 + colL] = acB[fj][r];
            }
        }
        __syncthreads();

        float hn0, hn1;
        {   // elementwise: 2 elements per thread; c lives in registers; plain cached loads
            #pragma unroll
            for (int e = 0; e < 2; ++e){
                int rowX = rowE + e*8;
                int growX = e ? growE1 : growE0;
                float cv = e ? creg1 : creg0;
                size_t gidx = (size_t)growX*Hh + gcol;
                float u0 = u_lds[(0*16 + rowX)*33 + colE];
                float u1 = u_lds[(1*16 + rowX)*33 + colE];
                float u2 = u_lds[(2*16 + rowX)*33 + colE];
                float e0 = __expf(tanhf_(u0*cv + ba));
                float e1 = __expf(tanhf_(u1*cv + ba));
                float e2 = __expf(tanhf_(u2*cv + ba));
                float inv = 1.f/(e0 + e1 + e2);
                float l0 = A.l_f[gidx];
                float l1 = A.l_f[(size_t)BH + gidx];
                float l2 = A.l_f[(size_t)2*BH + gidx];
                float fg = A.fo_f[gidx];
                float og = A.fo_f[(size_t)BH + gidx];
                float L = (e0*l0 + e1*l1 + e2*l2)*inv;
                float cn = fg*cv + L;
                float hn = og*tanhf_(cn);
                if (e) creg1 = cn; else creg0 = cn;
                __builtin_nontemporal_store(hn, &A.out[(size_t)BH + ((size_t)growX*Tt + t)*Hh + gcol]);
                if (t == Tt - 1) __builtin_nontemporal_store(hn, &A.out[gidx]);
                if (e) hn1 = hn; else hn0 = hn;
            }
        }
        __syncthreads();                       // everyone done reading u_lds
        {   // repack h tile to bf16 and store into block-exclusive chunk
            ushort_t* hrep = (ushort_t*)u_lds;  // 16x32 u16
            hrep[rowE*32 + colE]      = f2bf(hn0);
            hrep[(rowE+8)*32 + colE]  = f2bf(hn1);
            __syncthreads();
            // chunk [c2]: rows (grow0 + rs*16 .. +16); 16 u32/row
            uint32_t* dst = hbf32 + ((size_t)c2*Bb + grow0 + rs*16)*16;
            int lr = tid >> 4, cp = tid & 15;
            st_u32(dst + (size_t)lr*16 + cp, ((const uint32_t*)hrep)[tid]);
        }

        if (t != Tt - 1) group_barrier(gflags, gb, (uint32_t)(2*t + 2));
    }
}

extern "C" void kernel_launch(void* const* d_in, const int* in_sizes, int n_in,
                              void* d_out, int out_size, void* d_ws, size_t ws_size,
                              hipStream_t stream){
    const float* in[29];
    for (int i = 0; i < 29; ++i) in[i] = (const float*)d_in[i];

    char* ws = (char*)d_ws;
    ushort_t* wpack = (ushort_t*)(ws + 0);         // 9*MATSZ*2 = 5,898,240 B
    ushort_t* hbf   = (ushort_t*)(ws + 5898240);   //   262,144 B (chunked)
    ushort_t* l_bf  = (ushort_t*)(ws + 6160384);   //   786,432 B (chunked)
    float*    l_f   = (float*)   (ws + 6946816);   // 1,572,864 B
    float*    fo_f  = (float*)   (ws + 8519680);   // 1,048,576 B
    uint32_t* bar   = (uint32_t*)(ws + 9568256);   //    32,768 B (padded flags)
    // total ~9.6 MB of d_ws

    // mats: 0:i 1:i_p 2:i_n 3:f 4:c 5:c_p 6:c_n 7:o (K=640, [W;U]) ; 8: W_a (K=512)
    static const int WI[9] = {0, 3, 6, 9, 12, 15, 18, 21, 24};
    static const int UI[9] = {1, 4, 7, 10, 13, 16, 19, 22, -1};
    for (int m = 0; m < 9; ++m){
        int Ktot = (m == 8) ? Hh : KGATE;
        const float* Um = (m == 8) ? nullptr : in[UI[m]];
        int groups = Ktot*64;
        pack_mat<<<dim3((groups + 255)/256), dim3(256), 0, stream>>>(
            in[WI[m]], Um, Ktot, wpack + (size_t)m*MATSZ);
    }
    init_state2<<<dim3(BH/256), dim3(256), 0, stream>>>(hbf, bar);

    PK pk;
    pk.wpack = wpack;
    pk.X0 = in[26]; pk.X1 = in[27]; pk.X2 = in[28];
    pk.bC0 = in[14]; pk.bC1 = in[17]; pk.bC2 = in[20];
    pk.bI0 = in[2];  pk.bI1 = in[5];  pk.bI2 = in[8];
    pk.bF = in[11]; pk.bO = in[23]; pk.b_a = in[25];
    pk.hbf = hbf; pk.l_bf = l_bf; pk.l_f = l_f; pk.fo_f = fo_f;
    pk.bar = bar; pk.out = (float*)d_out;

    hipFuncSetAttribute((const void*)lstm_persistent,
                        hipFuncAttributeMaxDynamicSharedMemorySize, LDSB);
    void* args[] = { &pk };
    hipLaunchCooperativeKernel((const void*)lstm_persistent,
                               dim3(256), dim3(256), args, LDSB, stream);
}